// Round 7
// baseline (208.926 us; speedup 1.0000x reference)
//
#include <hip/hip_runtime.h>

// STDP learner: tr_pre/tr_post elementwise + delta_w = 0.5*w*(conv-wgrad pair).
// delta_w[o,i,kh,kw] = 0.5*w[o,i,kh,kw] *
//   sum_{b,p,q} tpre[b,i,p+kh,q+kw]*out[b,o,p,q] - tpost[b,o,p,q]*in[b,i,p+kh,q+kw]
// Sizes: B=16 CIN=64 H=W=66 COUT=128 HO=WO=64 KH=KW=3
// out layout: [tr_pre 4460544][tr_post 8388608][delta_w 73728]
//
// R12: DELETE the fill role (R11 post-mortem: fill re-reads the exact 103MB
// the mfma role already reads -- out/tpost == A operand, tpre/in == B rows;
// L3 holds all inputs, so fill was pure redundant traffic). Fuse:
//  - tr_post = 0.5*tpost + out: computed from the kh=0 blocks' A registers
//    (full coverage of (b,o,p,q)); 8 float4 stores/thread/stage.
//  - tr_pre = 0.5*tpre + in: computed inside stageB from the staged B rows;
//    gated (kh==0 || h==63+kh) for unique coverage incl. rows 64/65
//    (kh=1@p0=56 writes h=64, kh=2@p0=56 writes h=65).
//  - grid 2176 -> 384 (mfma blocks only); all NT hints reverted (R11: -6us).
//  - !use_ws fallback: separate k_fill_fb + k_naive launches (perf moot).
// Everything else verbatim R7 (proven 85.7us k_main): B fp32->cvt->LDS dbuf,
// 1 __syncthreads/stage; A global->reg cvt-at-use; 128-way fp32 partials.

typedef unsigned short ushort_t;
typedef unsigned int uint_t;
typedef __attribute__((ext_vector_type(8))) short short8;
typedef __attribute__((ext_vector_type(4))) float floatx4;
typedef __attribute__((ext_vector_type(2))) float floatx2;
typedef __attribute__((ext_vector_type(4))) int intx4;
typedef __attribute__((ext_vector_type(4))) uint_t uintx4;

#define N_POST   8388608     // 16*128*64*64
#define N_DW     73728       // 128*64*9
#define O_TRPOST 4460544
#define O_DW     12849152

#define MFMA_BLOCKS  384     // 3 kh * 128 (b,p0); kh=bx>>7 keeps twins same XCD
#define FB_FILLA 1024
#define FB_FILLB 768
#define B_ROWS_PER_WAVE 22   // 768*4*22 = 67584 rows exactly

// packed fp32->bf16, HW RNE (same rounding as bit-twiddle f2bf)
__device__ __forceinline__ int cvt2bf(float lo, float hi) {
  int r; asm("v_cvt_pk_bf16_f32 %0, %1, %2" : "=v"(r) : "v"(lo), "v"(hi)); return r;
}
__device__ __forceinline__ int cvt2bfn(float lo, float hi) {   // negated (free VOP3 mods)
  int r; asm("v_cvt_pk_bf16_f32 %0, -%1, -%2" : "=v"(r) : "v"(lo), "v"(hi)); return r;
}
// bytes [2..5] of (hi:lo) -- one v_alignbit_b32
__device__ __forceinline__ int bsh2(int hi, int lo) {
  return (int)((((unsigned long long)(uint_t)hi << 32) | (uint_t)lo) >> 16);
}

// ---- fused MFMA + elementwise kernel (grid 384) -----------------------------
// grid x -> kh = bx0>>7, bx = bx0&127 -> b = bx>>3, p0 = (bx&7)*8.
// block 256 = 4 waves, wave w owns o in [w*32, w*32+32). Per stage (p-row):
//   A (out,tpost): 16x dwordx4 global->reg, cvt at use; kh=0 also writes
//     tr_post from these registers.
//   B (tpre,in): 64 i-rows x 66 fp32 -> cvt -> LDS, double-buffered;
//     writer blocks also store tr_pre from the loaded registers.
// LB layout: [buf][i][mat*72 + e] shorts, row stride 304B (2-way banks=free)
__global__ __launch_bounds__(256, 2)
void k_main(const float* __restrict__ in_sp, const float* __restrict__ out_sp,
            const float* __restrict__ tpre, const float* __restrict__ tpost,
            float* __restrict__ o_trpre, float* __restrict__ o_trpost,
            float* __restrict__ partials) {
  __shared__ short LB[2][9728];                        // 38 KB
  const int bx0 = blockIdx.x;
  const int t = threadIdx.x;
  const int kh = bx0 >> 7, bx = bx0 & 127;
  const int b = bx >> 3, p0 = (bx & 7) * 8;
  const int w = t >> 6, l = t & 63;
  const int quad = l >> 4, l16 = l & 15;
  const int si = t >> 2, sg = t & 3;                   // B-stage: i row, 16-col seg

  const size_t abase = ((size_t)(b * 128 + w * 32 + l16)) * 4096 + quad * 8 + p0 * 64;
  const float* arow0 = out_sp + abase;
  const float* arow1 = tpost  + abase;
  float*       otp   = o_trpost + abase;
  const int wpost = (kh == 0);

  const size_t bbase = ((size_t)(b * 64 + si)) * 4356 + sg * 16;
  const float* brow0 = tpre  + bbase;
  const float* brow1 = in_sp + bbase;
  float*       opre0 = o_trpre + bbase;
  short* Lrow = &LB[0][0] + si * 152 + sg * 16;        // + buf*9728 + mat*72

  floatx4 acc[3][2][4] = {};                           // [kw][mt][nt]

  auto stageB = [&](int h, int buf) {
    const float* r0 = brow0 + h * 66;
    const float* r1 = brow1 + h * 66;
    const bool wp = (kh == 0) || (h == 63 + kh);       // unique tr_pre writer
    float* opre = opre0 + h * 66;
    floatx2 v0[8], v1[8];
    #pragma unroll
    for (int k = 0; k < 8; ++k) {                      // rows only 8B-aligned
      v0[k] = *(const floatx2*)(r0 + 2 * k);
      v1[k] = *(const floatx2*)(r1 + 2 * k);
    }
    if (wp) {
      #pragma unroll
      for (int k = 0; k < 8; ++k) {
        floatx2 v = { 0.5f * v0[k].x + v1[k].x, 0.5f * v0[k].y + v1[k].y };
        *(floatx2*)(opre + 2 * k) = v;
      }
    }
    uintx4 u0a = { (uint_t)cvt2bf(v0[0].x, v0[0].y), (uint_t)cvt2bf(v0[1].x, v0[1].y),
                   (uint_t)cvt2bf(v0[2].x, v0[2].y), (uint_t)cvt2bf(v0[3].x, v0[3].y) };
    uintx4 u0b = { (uint_t)cvt2bf(v0[4].x, v0[4].y), (uint_t)cvt2bf(v0[5].x, v0[5].y),
                   (uint_t)cvt2bf(v0[6].x, v0[6].y), (uint_t)cvt2bf(v0[7].x, v0[7].y) };
    uintx4 u1a = { (uint_t)cvt2bf(v1[0].x, v1[0].y), (uint_t)cvt2bf(v1[1].x, v1[1].y),
                   (uint_t)cvt2bf(v1[2].x, v1[2].y), (uint_t)cvt2bf(v1[3].x, v1[3].y) };
    uintx4 u1b = { (uint_t)cvt2bf(v1[4].x, v1[4].y), (uint_t)cvt2bf(v1[5].x, v1[5].y),
                   (uint_t)cvt2bf(v1[6].x, v1[6].y), (uint_t)cvt2bf(v1[7].x, v1[7].y) };
    short* Lb = Lrow + buf * 9728;
    *(uintx4*)(Lb)      = u0a;                         // mat0 = tpre
    *(uintx4*)(Lb + 8)  = u0b;
    *(uintx4*)(Lb + 72) = u1a;                         // mat1 = in
    *(uintx4*)(Lb + 80) = u1b;
    if (sg == 3) {                                     // elems 64,65
      floatx2 t0 = *(const floatx2*)(r0 + 16);
      floatx2 t1 = *(const floatx2*)(r1 + 16);
      *(uint_t*)(Lb + 16) = (uint_t)cvt2bf(t0.x, t0.y);
      *(uint_t*)(Lb + 88) = (uint_t)cvt2bf(t1.x, t1.y);
      if (wp) {
        floatx2 v = { 0.5f * t0.x + t1.x, 0.5f * t0.y + t1.y };
        *(floatx2*)(opre + 16) = v;
      }
    }
  };

  stageB(p0 + kh, 0);
  __syncthreads();

  for (int rr = 0; rr < 8; ++rr) {
    // A loads for this stage (issued first; latency hides under B staging)
    floatx4 ar[2][2][2][2];                            // [mat][mt][ks][half]
    #pragma unroll
    for (int mt = 0; mt < 2; ++mt)
      #pragma unroll
      for (int ks = 0; ks < 2; ++ks)
        #pragma unroll
        for (int hf = 0; hf < 2; ++hf) {
          const int off = rr * 64 + mt * 65536 + ks * 32 + hf * 4;
          ar[0][mt][ks][hf] = *(const floatx4*)(arow0 + off);
          ar[1][mt][ks][hf] = *(const floatx4*)(arow1 + off);
        }
    if (wpost) {                                       // tr_post from A regs
      #pragma unroll
      for (int mt = 0; mt < 2; ++mt)
        #pragma unroll
        for (int ks = 0; ks < 2; ++ks)
          #pragma unroll
          for (int hf = 0; hf < 2; ++hf) {
            const int off = rr * 64 + mt * 65536 + ks * 32 + hf * 4;
            floatx4 v = 0.5f * ar[1][mt][ks][hf] + ar[0][mt][ks][hf];
            *(floatx4*)(otp + off) = v;
          }
    }
    if (rr < 7) stageB(p0 + rr + 1 + kh, (rr + 1) & 1);

    const short* Lbb = &LB[0][0] + (rr & 1) * 9728;
    #pragma unroll
    for (int ks = 0; ks < 2; ++ks) {
      short8 fa[2][2];                                 // [mat][mt]
      #pragma unroll
      for (int mt = 0; mt < 2; ++mt) {
        uintx4 ua = { (uint_t)cvt2bf (ar[0][mt][ks][0].x, ar[0][mt][ks][0].y),
                      (uint_t)cvt2bf (ar[0][mt][ks][0].z, ar[0][mt][ks][0].w),
                      (uint_t)cvt2bf (ar[0][mt][ks][1].x, ar[0][mt][ks][1].y),
                      (uint_t)cvt2bf (ar[0][mt][ks][1].z, ar[0][mt][ks][1].w) };
        uintx4 un = { (uint_t)cvt2bfn(ar[1][mt][ks][0].x, ar[1][mt][ks][0].y),
                      (uint_t)cvt2bfn(ar[1][mt][ks][0].z, ar[1][mt][ks][0].w),
                      (uint_t)cvt2bfn(ar[1][mt][ks][1].x, ar[1][mt][ks][1].y),
                      (uint_t)cvt2bfn(ar[1][mt][ks][1].z, ar[1][mt][ks][1].w) };
        fa[0][mt] = __builtin_bit_cast(short8, ua);    // A1 = out
        fa[1][mt] = __builtin_bit_cast(short8, un);    // A2 = -tpost
      }
      #pragma unroll
      for (int nt = 0; nt < 4; ++nt) {
        const int i = nt * 16 + l16;
        short8 fb[2][3];                               // [mat][kw]
        #pragma unroll
        for (int mat = 0; mat < 2; ++mat) {
          const int base = i * 152 + mat * 72 + ks * 32 + quad * 8;
          intx4 W = *(const intx4*)&Lbb[base];
          int W4 = *(const int*)&Lbb[base + 8];
          intx4 f0 = { W.x, W.y, W.z, W.w };
          intx4 f1 = { bsh2(W.y, W.x), bsh2(W.z, W.y), bsh2(W.w, W.z), bsh2(W4, W.w) };
          intx4 f2 = { W.y, W.z, W.w, W4 };
          fb[mat][0] = __builtin_bit_cast(short8, f0);
          fb[mat][1] = __builtin_bit_cast(short8, f1);
          fb[mat][2] = __builtin_bit_cast(short8, f2);
        }
        #pragma unroll
        for (int kw = 0; kw < 3; ++kw)
          #pragma unroll
          for (int mt = 0; mt < 2; ++mt) {
            acc[kw][mt][nt] = __builtin_amdgcn_mfma_f32_16x16x32_bf16(fa[0][mt], fb[0][kw], acc[kw][mt][nt], 0, 0, 0);
            acc[kw][mt][nt] = __builtin_amdgcn_mfma_f32_16x16x32_bf16(fa[1][mt], fb[1][kw], acc[kw][mt][nt], 0, 0, 0);
          }
      }
    }
    __syncthreads();                                   // buf reuse fence
  }

  // C/D layout: col(i)=lane&15, row(o within 16)=quad*4+reg (HW-verified)
  #pragma unroll
  for (int kw = 0; kw < 3; ++kw) {
    float* slice = partials + (size_t)((kh * 3 + kw) * 128 + bx) * 8192;
    #pragma unroll
    for (int mt = 0; mt < 2; ++mt)
      #pragma unroll
      for (int nt = 0; nt < 4; ++nt)
        #pragma unroll
        for (int rg = 0; rg < 4; ++rg) {
          const int o = w * 32 + mt * 16 + quad * 4 + rg;
          const int i = nt * 16 + l16;
          slice[o * 64 + i] = acc[kw][mt][nt][rg];
        }
  }
}

// ---- split-K reduction + finalize ------------------------------------------
__global__ void k_finalize(const float* __restrict__ partials,
                           const float* __restrict__ weight, float* __restrict__ dw) {
  int tid = blockIdx.x * 256 + threadIdx.x;            // < 73728
  int e = tid >> 13, oi = tid & 8191;
  float s = 0.f;
  #pragma unroll 8
  for (int c = 0; c < 128; ++c) s += partials[(size_t)(e * 128 + c) * 8192 + oi];
  int o = oi >> 6, i = oi & 63;
  int wi = (o * 64 + i) * 9 + e;
  dw[wi] = 0.5f * weight[wi] * s;
}

// ---- fallback fill (ws too small): plain elementwise ------------------------
__global__ __launch_bounds__(256)
void k_fill_fb(const float* __restrict__ in_sp, const float* __restrict__ out_sp,
               const float* __restrict__ tpre, const float* __restrict__ tpost,
               float* __restrict__ o_trpre, float* __restrict__ o_trpost) {
  const int bx = blockIdx.x;
  const int t = threadIdx.x;
  if (bx < FB_FILLA) {
    int i4 = bx * 256 + t;                             // 2097152 = 262144*8
    #pragma unroll
    for (int it = 0; it < 8; ++it, i4 += FB_FILLA * 256) {
      floatx4 o = *(const floatx4*)(out_sp + i4 * 4);
      floatx4 p = *(const floatx4*)(tpost + i4 * 4);
      *(floatx4*)(o_trpost + i4 * 4) = 0.5f * p + o;
    }
  } else {
    const int l = t & 63;
    if (l >= 33) return;
    const int wid = (bx - FB_FILLA) * 4 + (t >> 6);
    #pragma unroll 2
    for (int it = 0; it < B_ROWS_PER_WAVE; ++it) {
      const int g = (wid * B_ROWS_PER_WAVE + it) * 66 + l * 2;
      floatx2 a = *(const floatx2*)(tpre + g);
      floatx2 c = *(const floatx2*)(in_sp + g);
      floatx2 v = { 0.5f * a.x + c.x, 0.5f * a.y + c.y };
      *(floatx2*)(o_trpre + g) = v;
    }
  }
}

// ---- fallback (ws too small): slow fp32, zero scratch ----------------------
__global__ void k_naive(const float* __restrict__ out_sp, const float* __restrict__ tpost,
                        const float* __restrict__ tpre, const float* __restrict__ in_sp,
                        const float* __restrict__ weight, float* __restrict__ dw) {
  int tid = blockIdx.x * 256 + threadIdx.x;
  int e = tid >> 13, oi = tid & 8191;
  int o = oi >> 6, i = oi & 63;
  int kh = e / 3, kw = e - kh * 3;
  float acc = 0.f;
  for (int b = 0; b < 16; ++b)
    for (int p = 0; p < 64; ++p) {
      const float* ga = out_sp + ((b * 128 + o) * 64 + p) * 64;
      const float* gn = tpost + ((b * 128 + o) * 64 + p) * 64;
      const float* gb = tpre + ((b * 64 + i) * 66 + p + kh) * 66 + kw;
      const float* gm = in_sp + ((b * 64 + i) * 66 + p + kh) * 66 + kw;
      for (int q = 0; q < 64; ++q) acc += ga[q] * gb[q] - gn[q] * gm[q];
    }
  int wi = (o * 64 + i) * 9 + kh * 3 + kw;
  dw[wi] = 0.5f * weight[wi] * acc;
}

extern "C" void kernel_launch(void* const* d_in, const int* in_sizes, int n_in,
                              void* d_out, int out_size, void* d_ws, size_t ws_size,
                              hipStream_t stream) {
  const float* in_sp  = (const float*)d_in[0];
  const float* out_sp = (const float*)d_in[1];
  const float* tpre   = (const float*)d_in[2];
  const float* tpost  = (const float*)d_in[3];
  const float* weight = (const float*)d_in[4];
  float* out = (float*)d_out;
  float* o_trpre  = out;
  float* o_trpost = out + O_TRPOST;
  float* o_dw     = out + O_DW;

  // ws: partials only (9*128*8192 fp32 = 37.7MB)
  const size_t WS_NEED = (size_t)9 * 128 * 8192 * 4;
  const int use_mfma = (ws_size >= WS_NEED) ? 1 : 0;
  float* partials = (float*)d_ws;

  if (use_mfma) {
    k_main<<<MFMA_BLOCKS, 256, 0, stream>>>(in_sp, out_sp, tpre, tpost,
                                            o_trpre, o_trpost, partials);
    k_finalize<<<N_DW / 256, 256, 0, stream>>>(partials, weight, o_dw);
  } else {
    k_fill_fb<<<FB_FILLA + FB_FILLB, 256, 0, stream>>>(in_sp, out_sp, tpre, tpost,
                                                       o_trpre, o_trpost);
    k_naive<<<N_DW / 256, 256, 0, stream>>>(out_sp, tpost, tpre, in_sp, weight, o_dw);
  }
}

// Round 9
// 198.557 us; speedup vs baseline: 1.0522x; 1.0522x over previous
//
#include <hip/hip_runtime.h>

// STDP learner: tr_pre/tr_post elementwise + delta_w = 0.5*w*(conv-wgrad pair).
// delta_w[o,i,kh,kw] = 0.5*w[o,i,kh,kw] *
//   sum_{b,p,q} tpre[b,i,p+kh,q+kw]*out[b,o,p,q] - tpost[b,o,p,q]*in[b,i,p+kh,q+kw]
// Sizes: B=16 CIN=64 H=W=66 COUT=128 HO=WO=64 KH=KW=3
// out layout: [tr_pre 4460544][tr_post 8388608][delta_w 73728]
//
// R14: REVERT to R7 exactly (measured 197.8us total, k_main 85.7us, passed).
// Post-R13 matrix: every perturbation of this structure lost --
//   R8 barrier-free B: +36us (VMEM-issue bound); R9 split-K 32 + o-half:
//   +46us (duplicated staging); R10 lgkm-only barrier: WRONG; R11 NT hints:
//   +6us; R12 tr-store fusion: +11us (stores in vmcnt0 drains); R13 split-K
//   64 / 16-stage: WRONG (undiagnosed).
// Structure: merged kernel; 384 mfma blocks (B fp32->cvt->LDS double-buffer,
// 1 __syncthreads/stage; A global->reg, cvt at use) co-resident with 1792
// fill blocks (pure elementwise streams) -> fill hides mfma barrier stalls;
// 128-way fp32 partials + k_finalize. k_main = 240MB @ ~2.9 TB/s mixed-mix
// ceiling (measured across R6/R7/R11/R12 variants).

typedef unsigned short ushort_t;
typedef unsigned int uint_t;
typedef __attribute__((ext_vector_type(8))) short short8;
typedef __attribute__((ext_vector_type(4))) float floatx4;
typedef __attribute__((ext_vector_type(2))) float floatx2;
typedef __attribute__((ext_vector_type(4))) int intx4;
typedef __attribute__((ext_vector_type(4))) uint_t uintx4;

#define N_POST   8388608     // 16*128*64*64
#define N_DW     73728       // 128*64*9
#define O_TRPOST 4460544
#define O_DW     12849152

#define MFMA_BLOCKS  384     // 3 kh * 128 (b,p0)
#define FILLA_BLOCKS 1024
#define FILLB_BLOCKS 768
#define TOTAL_BLOCKS 2176
#define B_ROWS_PER_WAVE 22   // 768*4*22 = 67584 rows exactly

// packed fp32->bf16, HW RNE (same rounding as bit-twiddle f2bf)
__device__ __forceinline__ uint_t cvt2bf(float lo, float hi) {
  uint_t r; asm("v_cvt_pk_bf16_f32 %0, %1, %2" : "=v"(r) : "v"(lo), "v"(hi)); return r;
}
__device__ __forceinline__ uint_t cvt2bfn(float lo, float hi) {   // negated (free VOP3 mods)
  uint_t r; asm("v_cvt_pk_bf16_f32 %0, -%1, -%2" : "=v"(r) : "v"(lo), "v"(hi)); return r;
}
// bytes [2..5] of (hi:lo) -- one v_alignbit_b32
__device__ __forceinline__ int bsh2(int hi, int lo) {
  return (int)((((unsigned long long)(uint_t)hi << 32) | (uint_t)lo) >> 16);
}

// ---- merged kernel ---------------------------------------------------------
// bx < 384:        MFMA role (needs ws for partials)
// 384..1408:       elementwise tr_post (float4 grid-stride, 8 iters exact)
// 1408..2176:      elementwise tr_pre (wave-per-row, lanes 0..32 x float2)
__global__ __launch_bounds__(256, 2)
void k_main(const float* __restrict__ in_sp, const float* __restrict__ out_sp,
            const float* __restrict__ tpre, const float* __restrict__ tpost,
            float* __restrict__ o_trpre, float* __restrict__ o_trpost,
            float* __restrict__ partials, int use_ws) {
  const int bx0 = blockIdx.x;
  const int t = threadIdx.x;

  if (bx0 >= MFMA_BLOCKS) {
    if (bx0 < MFMA_BLOCKS + FILLA_BLOCKS) {
      int i4 = (bx0 - MFMA_BLOCKS) * 256 + t;          // 2097152 = 262144*8
      #pragma unroll
      for (int it = 0; it < 8; ++it, i4 += FILLA_BLOCKS * 256) {
        floatx4 o = *(const floatx4*)(out_sp + i4 * 4);
        floatx4 p = *(const floatx4*)(tpost + i4 * 4);
        *(floatx4*)(o_trpost + i4 * 4) = 0.5f * p + o;
      }
    } else {
      const int l = t & 63;
      if (l >= 33) return;
      const int wid = (bx0 - (MFMA_BLOCKS + FILLA_BLOCKS)) * 4 + (t >> 6);
      #pragma unroll 2
      for (int it = 0; it < B_ROWS_PER_WAVE; ++it) {
        const int g = (wid * B_ROWS_PER_WAVE + it) * 66 + l * 2;
        floatx2 a = *(const floatx2*)(tpre + g);
        floatx2 c = *(const floatx2*)(in_sp + g);
        floatx2 v = { 0.5f * a.x + c.x, 0.5f * a.y + c.y };
        *(floatx2*)(o_trpre + g) = v;
      }
    }
    return;
  }
  if (!use_ws) return;                                 // fallback handles dw

  // ---- MFMA role: grid x -> kh = bx0>>7, bx = bx0&127 -> b = bx>>3, p0
  // block 256 = 4 waves, wave w owns o in [w*32, w*32+32). Per stage (p-row):
  //   A (out,tpost): 16x dwordx4 global->reg, cvt at use. No LDS (no reuse).
  //   B (tpre,in): 64 i-rows x 66 fp32 -> cvt -> LDS, double-buffered.
  // LB layout: [buf][i][mat*72 + e] shorts, row stride 304B (2-way banks=free)
  __shared__ short LB[2][9728];                        // 38 KB
  const int kh = bx0 >> 7, bx = bx0 & 127;
  const int b = bx >> 3, p0 = (bx & 7) * 8;
  const int w = t >> 6, l = t & 63;
  const int quad = l >> 4, l16 = l & 15;
  const int si = t >> 2, sg = t & 3;                   // B-stage: i row, 16-col seg

  const float* arow0 = out_sp + ((b * 128 + w * 32 + l16) * 4096 + quad * 8 + p0 * 64);
  const float* arow1 = tpost  + ((b * 128 + w * 32 + l16) * 4096 + quad * 8 + p0 * 64);
  const float* brow0 = tpre  + ((b * 64 + si) * 66 * 66 + sg * 16);
  const float* brow1 = in_sp + ((b * 64 + si) * 66 * 66 + sg * 16);
  short* Lrow = &LB[0][0] + si * 152 + sg * 16;        // + buf*9728 + mat*72

  floatx4 acc[3][2][4] = {};                           // [kw][mt][nt]

  auto stageB = [&](int h, int buf) {
    const float* r0 = brow0 + h * 66;
    const float* r1 = brow1 + h * 66;
    floatx2 v0[8], v1[8];
    #pragma unroll
    for (int k = 0; k < 8; ++k) {                      // rows only 8B-aligned
      v0[k] = *(const floatx2*)(r0 + 2 * k);
      v1[k] = *(const floatx2*)(r1 + 2 * k);
    }
    uintx4 u0a = { cvt2bf(v0[0].x, v0[0].y), cvt2bf(v0[1].x, v0[1].y),
                   cvt2bf(v0[2].x, v0[2].y), cvt2bf(v0[3].x, v0[3].y) };
    uintx4 u0b = { cvt2bf(v0[4].x, v0[4].y), cvt2bf(v0[5].x, v0[5].y),
                   cvt2bf(v0[6].x, v0[6].y), cvt2bf(v0[7].x, v0[7].y) };
    uintx4 u1a = { cvt2bf(v1[0].x, v1[0].y), cvt2bf(v1[1].x, v1[1].y),
                   cvt2bf(v1[2].x, v1[2].y), cvt2bf(v1[3].x, v1[3].y) };
    uintx4 u1b = { cvt2bf(v1[4].x, v1[4].y), cvt2bf(v1[5].x, v1[5].y),
                   cvt2bf(v1[6].x, v1[6].y), cvt2bf(v1[7].x, v1[7].y) };
    short* Lb = Lrow + buf * 9728;
    *(uintx4*)(Lb)      = u0a;                         // mat0 = tpre
    *(uintx4*)(Lb + 8)  = u0b;
    *(uintx4*)(Lb + 72) = u1a;                         // mat1 = in
    *(uintx4*)(Lb + 80) = u1b;
    if (sg == 3) {                                     // elems 64,65
      floatx2 t0 = *(const floatx2*)(r0 + 16);
      floatx2 t1 = *(const floatx2*)(r1 + 16);
      *(uint_t*)(Lb + 16) = cvt2bf(t0.x, t0.y);
      *(uint_t*)(Lb + 88) = cvt2bf(t1.x, t1.y);
    }
  };

  stageB(p0 + kh, 0);
  __syncthreads();

  for (int rr = 0; rr < 8; ++rr) {
    // A loads for this stage (issued first; latency hides under B staging)
    floatx4 ar[2][2][2][2];                            // [mat][mt][ks][half]
    #pragma unroll
    for (int mt = 0; mt < 2; ++mt)
      #pragma unroll
      for (int ks = 0; ks < 2; ++ks)
        #pragma unroll
        for (int hf = 0; hf < 2; ++hf) {
          const int off = rr * 64 + mt * 65536 + ks * 32 + hf * 4;
          ar[0][mt][ks][hf] = *(const floatx4*)(arow0 + off);
          ar[1][mt][ks][hf] = *(const floatx4*)(arow1 + off);
        }
    if (rr < 7) stageB(p0 + rr + 1 + kh, (rr + 1) & 1);

    const short* Lbb = &LB[0][0] + (rr & 1) * 9728;
    #pragma unroll
    for (int ks = 0; ks < 2; ++ks) {
      short8 fa[2][2];                                 // [mat][mt]
      #pragma unroll
      for (int mt = 0; mt < 2; ++mt) {
        uintx4 ua = { cvt2bf (ar[0][mt][ks][0].x, ar[0][mt][ks][0].y),
                      cvt2bf (ar[0][mt][ks][0].z, ar[0][mt][ks][0].w),
                      cvt2bf (ar[0][mt][ks][1].x, ar[0][mt][ks][1].y),
                      cvt2bf (ar[0][mt][ks][1].z, ar[0][mt][ks][1].w) };
        uintx4 un = { cvt2bfn(ar[1][mt][ks][0].x, ar[1][mt][ks][0].y),
                      cvt2bfn(ar[1][mt][ks][0].z, ar[1][mt][ks][0].w),
                      cvt2bfn(ar[1][mt][ks][1].x, ar[1][mt][ks][1].y),
                      cvt2bfn(ar[1][mt][ks][1].z, ar[1][mt][ks][1].w) };
        fa[0][mt] = __builtin_bit_cast(short8, ua);    // A1 = out
        fa[1][mt] = __builtin_bit_cast(short8, un);    // A2 = -tpost
      }
      #pragma unroll
      for (int nt = 0; nt < 4; ++nt) {
        const int i = nt * 16 + l16;
        short8 fb[2][3];                               // [mat][kw]
        #pragma unroll
        for (int mat = 0; mat < 2; ++mat) {
          const int base = i * 152 + mat * 72 + ks * 32 + quad * 8;
          intx4 W = *(const intx4*)&Lbb[base];
          int W4 = *(const int*)&Lbb[base + 8];
          intx4 f0 = { W.x, W.y, W.z, W.w };
          intx4 f1 = { bsh2(W.y, W.x), bsh2(W.z, W.y), bsh2(W.w, W.z), bsh2(W4, W.w) };
          intx4 f2 = { W.y, W.z, W.w, W4 };
          fb[mat][0] = __builtin_bit_cast(short8, f0);
          fb[mat][1] = __builtin_bit_cast(short8, f1);
          fb[mat][2] = __builtin_bit_cast(short8, f2);
        }
        #pragma unroll
        for (int kw = 0; kw < 3; ++kw)
          #pragma unroll
          for (int mt = 0; mt < 2; ++mt) {
            acc[kw][mt][nt] = __builtin_amdgcn_mfma_f32_16x16x32_bf16(fa[0][mt], fb[0][kw], acc[kw][mt][nt], 0, 0, 0);
            acc[kw][mt][nt] = __builtin_amdgcn_mfma_f32_16x16x32_bf16(fa[1][mt], fb[1][kw], acc[kw][mt][nt], 0, 0, 0);
          }
      }
    }
    __syncthreads();                                   // buf reuse fence
  }

  // C/D layout: col(i)=lane&15, row(o within 16)=quad*4+reg (HW-verified)
  #pragma unroll
  for (int kw = 0; kw < 3; ++kw) {
    float* slice = partials + (size_t)((kh * 3 + kw) * 128 + bx) * 8192;
    #pragma unroll
    for (int mt = 0; mt < 2; ++mt)
      #pragma unroll
      for (int nt = 0; nt < 4; ++nt)
        #pragma unroll
        for (int rg = 0; rg < 4; ++rg) {
          const int o = w * 32 + mt * 16 + quad * 4 + rg;
          const int i = nt * 16 + l16;
          slice[o * 64 + i] = acc[kw][mt][nt][rg];
        }
  }
}

// ---- split-K reduction + finalize ------------------------------------------
__global__ void k_finalize(const float* __restrict__ partials,
                           const float* __restrict__ weight, float* __restrict__ dw) {
  int tid = blockIdx.x * 256 + threadIdx.x;            // < 73728
  int e = tid >> 13, oi = tid & 8191;
  float s = 0.f;
  #pragma unroll 8
  for (int c = 0; c < 128; ++c) s += partials[(size_t)(e * 128 + c) * 8192 + oi];
  int o = oi >> 6, i = oi & 63;
  int wi = (o * 64 + i) * 9 + e;
  dw[wi] = 0.5f * weight[wi] * s;
}

// ---- fallback (ws too small): slow fp32, zero scratch ----------------------
__global__ void k_naive(const float* __restrict__ out_sp, const float* __restrict__ tpost,
                        const float* __restrict__ tpre, const float* __restrict__ in_sp,
                        const float* __restrict__ weight, float* __restrict__ dw) {
  int tid = blockIdx.x * 256 + threadIdx.x;
  int e = tid >> 13, oi = tid & 8191;
  int o = oi >> 6, i = oi & 63;
  int kh = e / 3, kw = e - kh * 3;
  float acc = 0.f;
  for (int b = 0; b < 16; ++b)
    for (int p = 0; p < 64; ++p) {
      const float* ga = out_sp + ((b * 128 + o) * 64 + p) * 64;
      const float* gn = tpost + ((b * 128 + o) * 64 + p) * 64;
      const float* gb = tpre + ((b * 64 + i) * 66 + p + kh) * 66 + kw;
      const float* gm = in_sp + ((b * 64 + i) * 66 + p + kh) * 66 + kw;
      for (int q = 0; q < 64; ++q) acc += ga[q] * gb[q] - gn[q] * gm[q];
    }
  int wi = (o * 64 + i) * 9 + kh * 3 + kw;
  dw[wi] = 0.5f * weight[wi] * acc;
}

extern "C" void kernel_launch(void* const* d_in, const int* in_sizes, int n_in,
                              void* d_out, int out_size, void* d_ws, size_t ws_size,
                              hipStream_t stream) {
  const float* in_sp  = (const float*)d_in[0];
  const float* out_sp = (const float*)d_in[1];
  const float* tpre   = (const float*)d_in[2];
  const float* tpost  = (const float*)d_in[3];
  const float* weight = (const float*)d_in[4];
  float* out = (float*)d_out;
  float* o_trpre  = out;
  float* o_trpost = out + O_TRPOST;
  float* o_dw     = out + O_DW;

  // ws: partials only (9*128*8192 fp32 = 37.7MB)
  const size_t WS_NEED = (size_t)9 * 128 * 8192 * 4;
  const int use_mfma = (ws_size >= WS_NEED) ? 1 : 0;
  float* partials = (float*)d_ws;

  k_main<<<TOTAL_BLOCKS, 256, 0, stream>>>(in_sp, out_sp, tpre, tpost,
                                           o_trpre, o_trpost, partials, use_mfma);
  if (use_mfma) {
    k_finalize<<<N_DW / 256, 256, 0, stream>>>(partials, weight, o_dw);
  } else {
    k_naive<<<N_DW / 256, 256, 0, stream>>>(out_sp, tpost, tpre, in_sp, weight, o_dw);
  }
}